// Round 3
// baseline (560.037 us; speedup 1.0000x reference)
//
#include <hip/hip_runtime.h>
#include <math.h>

typedef float f32x4 __attribute__((ext_vector_type(4)));

// ---------------------------------------------------------------------------
// R14: wave-independent compute + store, zero cross-wave synchronization.
//
// R13 post-mortem: all 1024 blocks co-resident + per-block barriers =>
// device-wide phase alignment: the whole device computes (~store pipe idle),
// then the whole device stores (~VALU idle). Sum, not overlap. R11's partial
// cohort overlap explains why it was the fastest of R11/R12/R13.
//
// Fix: 2048 blocks x 64 threads (1 wave), 4 batches/wave, no cross-wave
// barriers anywhere (__syncthreads in a 1-wave block is just a waitcnt).
// Waves desynchronize naturally; each wave's ~5 us compute hides under the
// device-wide store stream. Compute per lane: freq(l) once, neurons l and
// l+64, acc[2][4]; weight rows straight from L2 (W1+W2 = 128 KB, resident).
// LDS 4 KB/block, ~8 blocks/CU.
//
// Numerics: identical accumulation order (k4 0..31, x/y/z/w, bias-seeded),
// identical double-exp embed, identical SiLU + store placement as R11/R13
// -> bitwise-same output.
// ---------------------------------------------------------------------------
__global__ __launch_bounds__(64) void k_fused(
    const float* __restrict__ t,
    const float* __restrict__ W1, const float* __restrict__ b1,
    const float* __restrict__ W2, const float* __restrict__ b2,
    float* __restrict__ out)
{
    __shared__ __attribute__((aligned(16))) float E [4 * 128]; // emb -> h2
    __shared__ __attribute__((aligned(16))) float H1[4 * 128];

    const int l    = threadIdx.x;        // lane 0..63
    const int base = blockIdx.x * 4;     // 4 batches per wave

    // ---- embedding: lane l owns freq l; 4 batches ----
    {
        double a   = (double)l * (6.907755278982137 / 63.0);
        float freq = (float)exp(a);
        float ang  = 6.2831853071795865f * freq;
        #pragma unroll
        for (int b = 0; b < 4; ++b) {
            float ph = t[base + b] * ang;
            float sv, cv;
            sincosf(ph, &sv, &cv);
            E[b * 128 + l]      = sv;
            E[b * 128 + 64 + l] = cv;
        }
    }
    __syncthreads();   // 1-wave block: waitcnt only, no cross-wave alignment

    // ---- layer 1: neurons r0=l, r1=l+64 over 4 batches ----
    {
        const f32x4* w0 = (const f32x4*)(W1 + l * 128);
        const f32x4* w1 = (const f32x4*)(W1 + (l + 64) * 128);
        float acc[2][4];
        float bv0 = b1[l], bv1 = b1[l + 64];
        #pragma unroll
        for (int b = 0; b < 4; ++b) { acc[0][b] = bv0; acc[1][b] = bv1; }
        #pragma unroll 8
        for (int k4 = 0; k4 < 32; ++k4) {
            f32x4 wa = w0[k4];
            f32x4 wb = w1[k4];
            #pragma unroll
            for (int b = 0; b < 4; ++b) {
                f32x4 ev = ((const f32x4*)(E + b * 128))[k4];  // LDS broadcast
                acc[0][b] = fmaf(wa.x, ev.x, acc[0][b]);
                acc[0][b] = fmaf(wa.y, ev.y, acc[0][b]);
                acc[0][b] = fmaf(wa.z, ev.z, acc[0][b]);
                acc[0][b] = fmaf(wa.w, ev.w, acc[0][b]);
                acc[1][b] = fmaf(wb.x, ev.x, acc[1][b]);
                acc[1][b] = fmaf(wb.y, ev.y, acc[1][b]);
                acc[1][b] = fmaf(wb.z, ev.z, acc[1][b]);
                acc[1][b] = fmaf(wb.w, ev.w, acc[1][b]);
            }
        }
        #pragma unroll
        for (int b = 0; b < 4; ++b) {
            float a0 = acc[0][b], a1 = acc[1][b];
            H1[b * 128 + l]      = a0 / (1.0f + expf(-a0));   // SiLU
            H1[b * 128 + 64 + l] = a1 / (1.0f + expf(-a1));
        }
    }
    __syncthreads();

    // ---- layer 2: same mapping, W2/b2, H1 -> E (h2) ----
    {
        const f32x4* w0 = (const f32x4*)(W2 + l * 128);
        const f32x4* w1 = (const f32x4*)(W2 + (l + 64) * 128);
        float acc[2][4];
        float bv0 = b2[l], bv1 = b2[l + 64];
        #pragma unroll
        for (int b = 0; b < 4; ++b) { acc[0][b] = bv0; acc[1][b] = bv1; }
        #pragma unroll 8
        for (int k4 = 0; k4 < 32; ++k4) {
            f32x4 wa = w0[k4];
            f32x4 wb = w1[k4];
            #pragma unroll
            for (int b = 0; b < 4; ++b) {
                f32x4 ev = ((const f32x4*)(H1 + b * 128))[k4];
                acc[0][b] = fmaf(wa.x, ev.x, acc[0][b]);
                acc[0][b] = fmaf(wa.y, ev.y, acc[0][b]);
                acc[0][b] = fmaf(wa.z, ev.z, acc[0][b]);
                acc[0][b] = fmaf(wa.w, ev.w, acc[0][b]);
                acc[1][b] = fmaf(wb.x, ev.x, acc[1][b]);
                acc[1][b] = fmaf(wb.y, ev.y, acc[1][b]);
                acc[1][b] = fmaf(wb.z, ev.z, acc[1][b]);
                acc[1][b] = fmaf(wb.w, ev.w, acc[1][b]);
            }
        }
        #pragma unroll
        for (int b = 0; b < 4; ++b) {
            float a0 = acc[0][b], a1 = acc[1][b];
            E[b * 128 + l]      = a0 / (1.0f + expf(-a0));
            E[b * 128 + 64 + l] = a1 / (1.0f + expf(-a1));
        }
    }
    __syncthreads();

    // ---- store: 4 images x 64 KB. Image = 4096 f32x4; lane writes chunks
    // c*64+l; in-row column ((c*64+l)&31 = l&31) invariant -> v loaded once.
    #pragma unroll
    for (int b = 0; b < 4; ++b) {
        f32x4 v  = *(const f32x4*)&E[b * 128 + (l & 31) * 4];
        f32x4* d = (f32x4*)(out + (size_t)(base + b) * 16384);
        #pragma unroll
        for (int c = 0; c < 64; ++c) {
            d[c * 64 + l] = v;
        }
    }
}

extern "C" void kernel_launch(void* const* d_in, const int* in_sizes, int n_in,
                              void* d_out, int out_size, void* d_ws, size_t ws_size,
                              hipStream_t stream) {
    const float* t  = (const float*)d_in[0];
    const float* W1 = (const float*)d_in[1];
    const float* b1 = (const float*)d_in[2];
    const float* W2 = (const float*)d_in[3];
    const float* b2 = (const float*)d_in[4];
    float* out = (float*)d_out;
    const int B = in_sizes[0];   // 8192

    k_fused<<<B / 4, 64, 0, stream>>>(t, W1, b1, W2, b2, out);
}